// Round 5
// baseline (745.490 us; speedup 1.0000x reference)
//
#include <hip/hip_runtime.h>

#define VOCAB 33
#define EMBED 200
#define HIDDEN 200
#define BATCH 256
#define SEQ 1024
#define KW 50               // k-slice per wave
#define NW 4                // waves per block
#define LBUF 64             // logit steps buffered in LDS between flushes

typedef _Float16 h2 __attribute__((ext_vector_type(2)));

static __device__ __forceinline__ float fdot2f(h2 a, h2 b, float c) {
#if __has_builtin(__builtin_amdgcn_fdot2)
    return __builtin_amdgcn_fdot2(a, b, c, false);
#else
    return fmaf((float)a.x, (float)b.x, fmaf((float)a.y, (float)b.y, c));
#endif
}

// ---------------------------------------------------------------------------
// Kernel A: Ep[v][j] = sum_e embedding[v][e] * W_e[e][j]   (33 x 200 GEMM)
// ---------------------------------------------------------------------------
__global__ __launch_bounds__(256) void ep_kernel(const float* __restrict__ emb,
                                                 const float* __restrict__ We,
                                                 float* __restrict__ Ep) {
    const int v = blockIdx.x;     // 0..32
    const int j = threadIdx.x;    // 0..255
    if (j >= HIDDEN) return;
    float acc = 0.f;
    const float* er = emb + v * EMBED;
    for (int e = 0; e < EMBED; ++e)
        acc = fmaf(er[e], We[e * HIDDEN + j], acc);
    Ep[v * HIDDEN + j] = acc;
}

// ---------------------------------------------------------------------------
// Kernel B: per-batch-row RNN scan, k-split across 4 waves, f16 dot2 math.
//   - wave w owns k in [50w,50w+50) as 25 f16x2 pairs; lane l owns output
//     cols {l,64+l,128+l,192+l}; slot3 doubles as W_o columns (logits)
//   - h pair packed f16x2 per lane (<25); broadcast via readlane -> fdot2
//   - ZERO VMEM in the serial loop: logits buffered in LDS, flushed every
//     64 steps (kills the per-step vmcnt(0) drain at the barrier)
//   - one barrier per step; part[] double-buffered
// ---------------------------------------------------------------------------
__global__ __launch_bounds__(256, 1) void rnn_kernel(
    const int*   __restrict__ x,
    const float* __restrict__ hidden0,
    const float* __restrict__ Wh,
    const float* __restrict__ Wo,
    const float* __restrict__ Ep,      // may be nullptr -> compute in-block
    const float* __restrict__ emb,     // used only when Ep == nullptr
    const float* __restrict__ We,      // used only when Ep == nullptr
    float*       __restrict__ out)
{
    __shared__ float ep_s[VOCAB * HIDDEN];       // 26400 B (also emb staging)
    __shared__ float part[2][NW][256];           // 8192 B
    __shared__ float lbuf[LBUF * VOCAB];         // 8448 B logit staging
    __shared__ int   xs[SEQ + 1];                // 4100 B

    const int b   = blockIdx.x;
    const int tid = threadIdx.x;
    const int w   = tid >> 6;        // wave 0..3
    const int l   = tid & 63;        // lane 0..63
    const int k0  = w * KW;          // wave's k-slice base

    // --- Ep into LDS: load precomputed, or compute per-block ---
    if (Ep != nullptr) {
        for (int o = tid; o < VOCAB * HIDDEN; o += 256) ep_s[o] = Ep[o];
    } else {
        for (int o = tid; o < VOCAB * EMBED; o += 256) ep_s[o] = emb[o];
        __syncthreads();
        float acc[VOCAB];
        if (tid < HIDDEN) {
            #pragma unroll
            for (int v = 0; v < VOCAB; ++v) acc[v] = 0.f;
            for (int e = 0; e < EMBED; ++e) {
                const float we = We[e * HIDDEN + tid];
                #pragma unroll
                for (int v = 0; v < VOCAB; ++v)
                    acc[v] = fmaf(ep_s[v * EMBED + e], we, acc[v]);
            }
        }
        __syncthreads();
        if (tid < HIDDEN) {
            #pragma unroll
            for (int v = 0; v < VOCAB; ++v) ep_s[v * HIDDEN + tid] = acc[v];
        }
    }

    // --- stage x row (pad one zero entry to kill per-step bounds select) ---
    for (int o = tid; o < SEQ + 1; o += 256) xs[o] = (o < SEQ) ? x[b * SEQ + o] : 0;

    // --- register-resident W slice, f16x2 packed along k pairs ---
    h2 w0[25], w1[25], w2[25], w3[25];
    #pragma unroll
    for (int p = 0; p < 25; ++p) {
        const int kr = k0 + 2 * p;
        const float* r0 = Wh + (size_t)kr * HIDDEN;
        const float* r1 = r0 + HIDDEN;
        w0[p] = h2{(_Float16)r0[l],        (_Float16)r1[l]};
        w1[p] = h2{(_Float16)r0[64 + l],   (_Float16)r1[64 + l]};
        w2[p] = h2{(_Float16)r0[128 + l],  (_Float16)r1[128 + l]};
        float b0, b1;
        if (l < 8)       { b0 = r0[192 + l];              b1 = r1[192 + l]; }
        else if (l < 41) { b0 = Wo[kr * VOCAB + (l - 8)]; b1 = Wo[(kr + 1) * VOCAB + (l - 8)]; }
        else             { b0 = 0.f;                      b1 = 0.f; }
        w3[p] = h2{(_Float16)b0, (_Float16)b1};
    }

    // --- per-lane packed h pair: lane l<25 of wave w holds h[k0+2l..2l+1] ---
    float hn0 = 0.f, hn1 = 0.f;
    int hpi = 0;
    if (l < 25) {
        hn0 = hidden0[b * HIDDEN + k0 + 2 * l];
        hn1 = hidden0[b * HIDDEN + k0 + 2 * l + 1];
        hpi = __builtin_bit_cast(int, __builtin_amdgcn_cvt_pkrtz(hn0, hn1));
    }
    __syncthreads();

    const float LOG2E2 = 2.8853900817779268f;   // 2*log2(e)
    float* outb = out + (size_t)b * (SEQ * VOCAB);
    float* fh   = out + (size_t)BATCH * SEQ * VOCAB + (size_t)b * HIDDEN;
    const int vid = w * 14 + (l - 50);          // logit-reduce role (l>=50)

    int idx = xs[0];
    for (int t = 0; t < SEQ; ++t) {
        const int par = t & 1;

        // prefetch ep pair (consumed after barrier) + next idx (LDS only)
        float ep0 = 0.f, ep1 = 0.f;
        if (l < 25) {
            const float2 ev = *(const float2*)&ep_s[idx * HIDDEN + k0 + 2 * l];
            ep0 = ev.x; ep1 = ev.y;
        }
        const int idx_n = xs[t + 1];

        // ---- k-loop: 25 readlane + 100 dot2, zero LDS, zero VMEM ----
        float a0 = 0.f, a1 = 0.f, a2 = 0.f, a3 = 0.f;
        #pragma unroll
        for (int p = 0; p < 25; ++p) {
            const h2 hh = __builtin_bit_cast(h2,
                              __builtin_amdgcn_readlane(hpi, p));
            a0 = fdot2f(hh, w0[p], a0);
            a1 = fdot2f(hh, w1[p], a1);
            a2 = fdot2f(hh, w2[p], a2);
            a3 = fdot2f(hh, w3[p], a3);
        }

        // ---- write partials (lanes consecutive -> conflict-free) ----
        part[par][w][l]       = a0;
        part[par][w][64 + l]  = a1;
        part[par][w][128 + l] = a2;
        part[par][w][192 + l] = a3;
        __syncthreads();

        // ---- reduce: lanes <25 new h pair; lanes >=50 logits -> LDS buf ----
        if (l < 25) {
            const int j = k0 + 2 * l;
            const float2 p0 = *(const float2*)&part[par][0][j];
            const float2 p1 = *(const float2*)&part[par][1][j];
            const float2 p2 = *(const float2*)&part[par][2][j];
            const float2 p3 = *(const float2*)&part[par][3][j];
            const float z0 = (p0.x + p1.x) + (p2.x + p3.x) + ep0;
            const float z1 = (p0.y + p1.y) + (p2.y + p3.y) + ep1;
            const float e0 = __builtin_amdgcn_exp2f(z0 * LOG2E2);
            const float e1 = __builtin_amdgcn_exp2f(z1 * LOG2E2);
            hn0 = (e0 - 1.f) * __builtin_amdgcn_rcpf(e0 + 1.f);
            hn1 = (e1 - 1.f) * __builtin_amdgcn_rcpf(e1 + 1.f);
            hpi = __builtin_bit_cast(int, __builtin_amdgcn_cvt_pkrtz(hn0, hn1));
        } else if (l >= 50 && vid < VOCAB && t > 0) {
            const float s = part[par][0][200 + vid] + part[par][1][200 + vid]
                          + part[par][2][200 + vid] + part[par][3][200 + vid];
            lbuf[((t - 1) & (LBUF - 1)) * VOCAB + vid] = s;
        }
        idx = idx_n;

        // ---- flush 64 buffered logit rows (coalesced; once per 64 steps) ----
        if (t >= LBUF && (t & (LBUF - 1)) == 0) {
            __syncthreads();   // lbuf writes visible to all
            const size_t base = (size_t)(t - LBUF) * VOCAB;
            for (int f = tid; f < LBUF * VOCAB; f += 256)
                outb[base + f] = lbuf[f];
            // no trailing barrier needed: next lbuf write to any slot happens
            // only after the NEXT iteration's mid-step barrier
        }
    }

    // ---- epilogue: logits of final state into slot 63, final flush, fh ----
    {
        float a3 = 0.f;
        #pragma unroll
        for (int p = 0; p < 25; ++p) {
            const h2 hh = __builtin_bit_cast(h2,
                              __builtin_amdgcn_readlane(hpi, p));
            a3 = fdot2f(hh, w3[p], a3);
        }
        part[0][w][192 + l] = a3;
        __syncthreads();
        if (l >= 50 && vid < VOCAB) {
            const float s = part[0][0][200 + vid] + part[0][1][200 + vid]
                          + part[0][2][200 + vid] + part[0][3][200 + vid];
            lbuf[(LBUF - 1) * VOCAB + vid] = s;   // step SEQ-1 -> slot 63
        }
        __syncthreads();
        const size_t base = (size_t)(SEQ - LBUF) * VOCAB;
        for (int f = tid; f < LBUF * VOCAB; f += 256)
            outb[base + f] = lbuf[f];
        if (l < 25) {
            fh[k0 + 2 * l]     = hn0;
            fh[k0 + 2 * l + 1] = hn1;
        }
    }
}

// ---------------------------------------------------------------------------
extern "C" void kernel_launch(void* const* d_in, const int* in_sizes, int n_in,
                              void* d_out, int out_size, void* d_ws, size_t ws_size,
                              hipStream_t stream) {
    const int*   x   = (const int*)  d_in[0];
    const float* h0  = (const float*)d_in[1];
    const float* emb = (const float*)d_in[2];
    const float* We  = (const float*)d_in[3];
    const float* Wh  = (const float*)d_in[4];
    const float* Wo  = (const float*)d_in[5];
    float* out = (float*)d_out;

    const size_t ep_bytes = (size_t)VOCAB * HIDDEN * sizeof(float);
    float* ep = (ws_size >= ep_bytes) ? (float*)d_ws : nullptr;

    if (ep) ep_kernel<<<VOCAB, 256, 0, stream>>>(emb, We, ep);
    rnn_kernel<<<BATCH, 256, 0, stream>>>(x, h0, Wh, Wo, ep, emb, We, out);
}